// Round 2
// baseline (209.615 us; speedup 1.0000x reference)
//
#include <hip/hip_runtime.h>
#include <math.h>

// MoE router: x[16384,2048] fp32, W[8,2048] fp32 -> (top2 idx, top2 gates, logits)
// Memory-bound: 134 MB read-once. v2: 16 lanes/token, 4 tokens/wave, acc[8]/lane,
// zero LDS (shuffle reduce-scatter epilogue), 1024 blocks -> 4 blocks/CU resident.

constexpr int D      = 2048;
constexpr int E      = 8;
constexpr int T_W    = 4;               // tokens per wave
constexpr int LPT    = 16;              // lanes per token
constexpr int ITERS  = D / (LPT * 4);   // 32 iters, 4 dims/lane/iter
constexpr int TOKENS = 16384;

typedef float f32x4 __attribute__((ext_vector_type(4)));

__device__ __forceinline__ bool better(float va, int ia, float vb, int ib) {
    // jax.lax.top_k tie rule: larger value wins; equal values -> smaller index
    return (va > vb) || (va == vb && ia < ib);
}

__global__ __launch_bounds__(256, 4)
void moe_router_kernel(const float* __restrict__ x,
                       const float* __restrict__ w,
                       float* __restrict__ out)
{
    const int lane = threadIdx.x & 63;
    const int wave = threadIdx.x >> 6;
    const int tloc = lane >> 4;          // 0..3: token within wave
    const int g    = lane & 15;          // dim sublane within token group
    const int token = (blockIdx.x * 4 + wave) * T_W + tloc;

    const float* xp = x + (size_t)token * D + g * 4;
    const float* wp = w + g * 4;

    float acc[E];
#pragma unroll
    for (int e = 0; e < E; ++e) acc[e] = 0.0f;

    // Each iter: token-group of 16 lanes reads one 256B-contiguous x chunk.
    // W chunk (1 KB per e per iter) served by L1/L2 broadcast.
#pragma unroll 4
    for (int it = 0; it < ITERS; ++it) {
        const f32x4 xv = __builtin_nontemporal_load(
            reinterpret_cast<const f32x4*>(xp + it * (LPT * 4)));
#pragma unroll
        for (int e = 0; e < E; ++e) {
            const f32x4 wv =
                *reinterpret_cast<const f32x4*>(wp + e * D + it * (LPT * 4));
            float a = acc[e];
            a = fmaf(xv.x, wv.x, a);
            a = fmaf(xv.y, wv.y, a);
            a = fmaf(xv.z, wv.z, a);
            a = fmaf(xv.w, wv.w, a);
            acc[e] = a;
        }
    }

    // ---- Shuffle reduce-scatter over the 16-lane token group (masks 8,4,2,1).
    // m=8: collapse the two octets; both octets end up with identical state.
#pragma unroll
    for (int e = 0; e < E; ++e) acc[e] += __shfl_xor(acc[e], 8, 64);

    // m=4: keep the half matching (lane&4), send the other half to the partner.
    const bool s4 = (lane & 4) != 0;
    float r[4];
#pragma unroll
    for (int i = 0; i < 4; ++i) {
        const float keep = s4 ? acc[i + 4] : acc[i];
        const float send = s4 ? acc[i]     : acc[i + 4];
        r[i] = keep + __shfl_xor(send, 4, 64);   // r[i] <-> e = (lane&4) + i
    }
    // m=2
    const bool s2 = (lane & 2) != 0;
    float sr[2];
#pragma unroll
    for (int i = 0; i < 2; ++i) {
        const float keep = s2 ? r[i + 2] : r[i];
        const float send = s2 ? r[i]     : r[i + 2];
        sr[i] = keep + __shfl_xor(send, 2, 64);  // sr[i] <-> e = (lane&6) + i
    }
    // m=1
    const bool s1 = (lane & 1) != 0;
    float logit;
    {
        const float keep = s1 ? sr[1] : sr[0];
        const float send = s1 ? sr[0] : sr[1];
        logit = keep + __shfl_xor(send, 1, 64);  // logit <-> e = lane&7
    }

    const int  e      = lane & 7;
    const bool writer = (lane & 8) == 0;   // octet1 holds a duplicate

    float* out_idx    = out;                 // [TOKENS][2] (indices as fp32)
    float* out_gate   = out + TOKENS * 2;    // [TOKENS][2]
    float* out_logits = out + TOKENS * 4;    // [TOKENS][8]

    if (writer) out_logits[(size_t)token * E + e] = logit;

    // Top-2 across the 8 lanes of this octet (xor masks 1,2,4 stay in-octet).
    float v1 = logit, v2 = -INFINITY;
    int   i1 = e,     i2 = E;
#pragma unroll
    for (int m = 1; m <= 4; m <<= 1) {
        float ov1 = __shfl_xor(v1, m, 64);
        int   oi1 = __shfl_xor(i1, m, 64);
        float ov2 = __shfl_xor(v2, m, 64);
        int   oi2 = __shfl_xor(i2, m, 64);
        float nv1, nv2; int ni1, ni2;
        if (better(v1, i1, ov1, oi1)) {
            nv1 = v1; ni1 = i1;
            if (better(v2, i2, ov1, oi1)) { nv2 = v2;  ni2 = i2;  }
            else                          { nv2 = ov1; ni2 = oi1; }
        } else {
            nv1 = ov1; ni1 = oi1;
            if (better(ov2, oi2, v1, i1)) { nv2 = ov2; ni2 = oi2; }
            else                          { nv2 = v1;  ni2 = i1;  }
        }
        v1 = nv1; i1 = ni1; v2 = nv2; i2 = ni2;
    }

    // softmax over the 2 selected logits: [1, e^(v2-v1)] / (1 + e^(v2-v1))
    if (writer && e < 2) {
        const float ed  = expf(v2 - v1);          // v2 <= v1, so ed in (0,1]
        const float inv = 1.0f / (1.0f + ed);
        const float gte = (e == 0) ? inv : ed * inv;
        out_idx [token * 2 + e] = (float)((e == 0) ? i1 : i2);
        out_gate[token * 2 + e] = gte;
    }
}

extern "C" void kernel_launch(void* const* d_in, const int* in_sizes, int n_in,
                              void* d_out, int out_size, void* d_ws, size_t ws_size,
                              hipStream_t stream) {
    const float* x = (const float*)d_in[0];
    const float* w = (const float*)d_in[1];
    float* out = (float*)d_out;
    // 16384 tokens / (4 waves * 4 tokens) = 1024 blocks, 256 threads each.
    hipLaunchKernelGGL(moe_router_kernel, dim3(1024), dim3(256), 0, stream,
                       x, w, out);
}

// Round 3
// 194.676 us; speedup vs baseline: 1.0767x; 1.0767x over previous
//
#include <hip/hip_runtime.h>
#include <math.h>

// MoE router: x[16384,2048] fp32, W[8,2048] fp32 -> (top2 idx, top2 gates, logits)
// Memory-bound: 134 MB read-once. v3: v1's K-loop shape (64 lanes cover a 256-dim
// stripe, W-tile amortized over the wave's tokens) but T=4 tokens/wave ->
// 4096 waves (4/SIMD resident), acc[32]/lane, zero LDS (butterfly reduce-scatter).

constexpr int D      = 2048;
constexpr int E      = 8;
constexpr int T      = 4;       // tokens per wave
constexpr int WAVES  = 4;       // waves per block (256 threads)
constexpr int TOKENS = 16384;

typedef float f32x4 __attribute__((ext_vector_type(4)));

__device__ __forceinline__ bool better(float va, int ia, float vb, int ib) {
    // jax.lax.top_k tie rule: larger value wins; equal values -> smaller index
    return (va > vb) || (va == vb && ia < ib);
}

__global__ __launch_bounds__(256, 4)
void moe_router_kernel(const float* __restrict__ x,
                       const float* __restrict__ w,
                       float* __restrict__ out)
{
    const int lane = threadIdx.x & 63;
    const int wave = threadIdx.x >> 6;
    const int tok0 = (blockIdx.x * WAVES + wave) * T;

    float acc[T * E];
#pragma unroll
    for (int i = 0; i < T * E; ++i) acc[i] = 0.0f;

    // K loop: 8 iterations cover D=2048. Lane l handles dims it*256 + l*4 .. +3.
    // Per it: 4 x-loads (HBM stream) + 8 W-loads (L1/L2 resident), 128 FMAs.
#pragma unroll 4
    for (int it = 0; it < D / 256; ++it) {
        const int d = it * 256 + lane * 4;
        f32x4 xv[T];
#pragma unroll
        for (int t = 0; t < T; ++t)
            xv[t] = *reinterpret_cast<const f32x4*>(x + (size_t)(tok0 + t) * D + d);
#pragma unroll
        for (int e = 0; e < E; ++e) {
            const f32x4 wv = *reinterpret_cast<const f32x4*>(w + e * D + d);
#pragma unroll
            for (int t = 0; t < T; ++t) {
                float a = acc[t * E + e];
                a = fmaf(xv[t].x, wv.x, a);
                a = fmaf(xv[t].y, wv.y, a);
                a = fmaf(xv[t].z, wv.z, a);
                a = fmaf(xv[t].w, wv.w, a);
                acc[t * E + e] = a;
            }
        }
    }

    // ---- Butterfly reduce-scatter of 32 (token,expert) sums across 64 lanes.
    // m=32: collapse halves; both halves end identical (upper half = duplicates).
#pragma unroll
    for (int i = 0; i < 32; ++i) acc[i] += __shfl_xor(acc[i], 32, 64);

    // mask 16: keep the half of indices matching (lane&16), send the other half.
    const bool s16 = (lane & 16) != 0;
    float r16[16];
#pragma unroll
    for (int i = 0; i < 16; ++i) {
        const float keep = s16 ? acc[i + 16] : acc[i];
        const float send = s16 ? acc[i]      : acc[i + 16];
        r16[i] = keep + __shfl_xor(send, 16, 64);  // r16[i] <-> p = (lane&16)+i
    }
    const bool s8 = (lane & 8) != 0;
    float r8[8];
#pragma unroll
    for (int i = 0; i < 8; ++i) {
        const float keep = s8 ? r16[i + 8] : r16[i];
        const float send = s8 ? r16[i]     : r16[i + 8];
        r8[i] = keep + __shfl_xor(send, 8, 64);    // r8[i] <-> p = (lane&24)+i
    }
    const bool s4 = (lane & 4) != 0;
    float r4[4];
#pragma unroll
    for (int i = 0; i < 4; ++i) {
        const float keep = s4 ? r8[i + 4] : r8[i];
        const float send = s4 ? r8[i]     : r8[i + 4];
        r4[i] = keep + __shfl_xor(send, 4, 64);    // r4[i] <-> p = (lane&28)+i
    }
    const bool s2 = (lane & 2) != 0;
    float r2[2];
#pragma unroll
    for (int i = 0; i < 2; ++i) {
        const float keep = s2 ? r4[i + 2] : r4[i];
        const float send = s2 ? r4[i]     : r4[i + 2];
        r2[i] = keep + __shfl_xor(send, 2, 64);    // r2[i] <-> p = (lane&30)+i
    }
    const bool s1 = (lane & 1) != 0;
    float logit;
    {
        const float keep = s1 ? r2[1] : r2[0];
        const float send = s1 ? r2[0] : r2[1];
        logit = keep + __shfl_xor(send, 1, 64);    // logit <-> p = lane&31
    }

    // p = lane&31: token = tok0 + (p>>3), expert = p&7. Upper half duplicates.
    const int  e      = lane & 7;
    const int  t      = (lane >> 3) & 3;
    const int  token  = tok0 + t;
    const bool writer = lane < 32;

    float* out_idx    = out;                 // [TOKENS][2] (indices as fp32)
    float* out_gate   = out + TOKENS * 2;    // [TOKENS][2]
    float* out_logits = out + TOKENS * 4;    // [TOKENS][8]

    // lanes 0..31 write 32 consecutive floats: fully coalesced 128B.
    if (writer) out_logits[(size_t)tok0 * E + lane] = logit;

    // Top-2 across the 8 lanes of each octet (xor masks 1,2,4 stay in-octet).
    float v1 = logit, v2 = -INFINITY;
    int   i1 = e,     i2 = E;
#pragma unroll
    for (int m = 1; m <= 4; m <<= 1) {
        float ov1 = __shfl_xor(v1, m, 64);
        int   oi1 = __shfl_xor(i1, m, 64);
        float ov2 = __shfl_xor(v2, m, 64);
        int   oi2 = __shfl_xor(i2, m, 64);
        float nv1, nv2; int ni1, ni2;
        if (better(v1, i1, ov1, oi1)) {
            nv1 = v1; ni1 = i1;
            if (better(v2, i2, ov1, oi1)) { nv2 = v2;  ni2 = i2;  }
            else                          { nv2 = ov1; ni2 = oi1; }
        } else {
            nv1 = ov1; ni1 = oi1;
            if (better(ov2, oi2, v1, i1)) { nv2 = ov2; ni2 = oi2; }
            else                          { nv2 = v1;  ni2 = i1;  }
        }
        v1 = nv1; i1 = ni1; v2 = nv2; i2 = ni2;
    }

    // softmax over the 2 selected logits: [1, e^(v2-v1)] / (1 + e^(v2-v1))
    if (writer && e < 2) {
        const float ed  = expf(v2 - v1);          // v2 <= v1, so ed in (0,1]
        const float inv = 1.0f / (1.0f + ed);
        const float g   = (e == 0) ? inv : ed * inv;
        out_idx [token * 2 + e] = (float)((e == 0) ? i1 : i2);
        out_gate[token * 2 + e] = g;
    }
}

extern "C" void kernel_launch(void* const* d_in, const int* in_sizes, int n_in,
                              void* d_out, int out_size, void* d_ws, size_t ws_size,
                              hipStream_t stream) {
    const float* x = (const float*)d_in[0];
    const float* w = (const float*)d_in[1];
    float* out = (float*)d_out;
    // 16384 tokens / (4 waves * 4 tokens) = 1024 blocks, 256 threads each.
    hipLaunchKernelGGL(moe_router_kernel, dim3(1024), dim3(256), 0, stream,
                       x, w, out);
}